// Round 10
// baseline (339.697 us; speedup 1.0000x reference)
//
#include <hip/hip_runtime.h>
#include <hip/hip_bf16.h>

typedef __bf16 bf16;
typedef __attribute__((ext_vector_type(8))) __bf16 bf16x8;
typedef __attribute__((ext_vector_type(4))) __bf16 bf16x4;
typedef __attribute__((ext_vector_type(4))) float f32x4;

#define BAR() __builtin_amdgcn_s_barrier()

__device__ __forceinline__ void async_load16(const void* g, void* l) {
    __builtin_amdgcn_global_load_lds(
        (const __attribute__((address_space(1))) void*)g,
        (__attribute__((address_space(3))) void*)l, 16, 0, 0);
}

// ---------- kernel 1: per-block partial sum of |w| (deterministic tree) ----------
__global__ __launch_bounds__(256) void k_abs_part(const float* __restrict__ w, int n,
                                                  double* __restrict__ part) {
    __shared__ double sd[256];
    const int per_block = n / gridDim.x;
    const int base = blockIdx.x * per_block;
    double s = 0.0;
    for (int i = threadIdx.x; i < per_block; i += 256)
        s += (double)fabsf(w[base + i]);
    sd[threadIdx.x] = s;
    __syncthreads();
    for (int off = 128; off > 0; off >>= 1) {
        if (threadIdx.x < off) sd[threadIdx.x] += sd[threadIdx.x + off];
        __syncthreads();
    }
    if (threadIdx.x == 0) part[blockIdx.x] = sd[0];
}

// ---------- kernel 2: finalize delta locally + quantize W to ternary bf16 ----------
__global__ __launch_bounds__(256) void k_quantW(const float* __restrict__ w,
                                                const double* __restrict__ part,
                                                bf16* __restrict__ wt, int n4, int wn) {
    __shared__ double sd[256];
    sd[threadIdx.x] = part[threadIdx.x];
    __syncthreads();
    for (int off = 128; off > 0; off >>= 1) {
        if (threadIdx.x < off) sd[threadIdx.x] += sd[threadIdx.x + off];
        __syncthreads();
    }
    const float d = (float)(0.7 * sd[0] / (double)wn);
    const int stride = gridDim.x * 256;
    for (int i = blockIdx.x * 256 + threadIdx.x; i < n4; i += stride) {
        const float4 v = ((const float4*)w)[i];
        bf16x4 o;
        o[0] = (bf16)((v.x > d) ? 1.0f : (v.x < -d) ? -1.0f : 0.0f);
        o[1] = (bf16)((v.y > d) ? 1.0f : (v.y < -d) ? -1.0f : 0.0f);
        o[2] = (bf16)((v.z > d) ? 1.0f : (v.z < -d) ? -1.0f : 0.0f);
        o[3] = (bf16)((v.w > d) ? 1.0f : (v.w < -d) ? -1.0f : 0.0f);
        *(bf16x4*)(wt + (size_t)i * 4) = o;
    }
}

// ---------- helper: stage one 128x64 bf16 half-tile via global_load_lds, 512 thr ----
// Linear LDS dest; swizzle via inverse-permuted GLOBAL source 16B-slot
// s = (c&7) ^ ((t>>3)&7).  (rp&7)==((t>>3)&7) since rows advance by 64 per r-step.
__device__ __forceinline__ void stage_half(const bf16* __restrict__ srch, int K, int kt,
                                           char* dst, int t) {
    #pragma unroll
    for (int r = 0; r < 2; ++r) {
        const int c  = (r << 9) + t;
        const int rp = c >> 3;
        const int s  = (c & 7) ^ ((t >> 3) & 7);
        async_load16(srch + (size_t)rp * K + (kt << 6) + (s << 3), dst + (c << 4));
    }
}

// ---------- helper: stage one 128x64 FP32 A-tile via global_load_lds, 512 thr ----------
// 32KB = 2048 chunks of 16B, 4/thread.  Row = 256B = 16 slots; read-side XOR is
// ((row&7)<<1) on the slot index, so the source slot is s = (c&15) ^ ((rp&7)<<1).
// (rp&7) == ((t>>4)&7) since rows advance by 32 per r-step.
__device__ __forceinline__ void stage_Afp(const float* __restrict__ srch, int K, int kt,
                                          char* dst, int t) {
    #pragma unroll
    for (int r = 0; r < 4; ++r) {
        const int c  = (r << 9) + t;
        const int rp = c >> 4;
        const int s  = (c & 15) ^ (((t >> 4) & 7) << 1);
        async_load16(srch + (size_t)rp * K + (kt << 6) + (s << 2), dst + (c << 4));
    }
}

// ---------- kernel 3: fused GEMM, A staged as RAW FP32 via DMA, cvt at LDS read ----
// C[m][n] = alpha * sum_k A[m][k]*Wt[n][k] + bias[n].  BM=128 x BN=256, BK=64,
// 512 thr = 8 waves (2M x 4N), wave tile 64x64, acc 4x4.  LDS 64KB (A fp32 32K +
// B bf16 32K) single-buffered -> 2 blocks/CU.  Schedule = round-8 proven 2-phase:
// {RD ks0, MFMA ks0, RD ks1, lgkm0+BAR | stage t+1 (8 DMA/thr), MFMA ks1 (regs,
// hides DMA), vmcnt0, BAR}.  fp32->bf16 happens in RDA_F (VALU pipe, overlaps
// co-resident block's MFMA).  No separate convA pass.
__global__ __launch_bounds__(512, 4) void k_gemmH(const float* __restrict__ Afp,
                                                  const bf16* __restrict__ Bw,
                                                  const float* __restrict__ alphap,
                                                  const float* __restrict__ bias,
                                                  float* __restrict__ C,
                                                  int M, int N, int K) {
    __shared__ __align__(16) char As[32768];     // 128 x 64 fp32, swizzled (16 slots/row)
    __shared__ __align__(16) char Bs[32768];     // 256 x 64 bf16, swizzled (8 slots/row)

    const int t    = threadIdx.x;
    const int lane = t & 63;
    const int w    = t >> 6;
    const int wm   = w >> 2;          // 0/1: rows wm*64..+63
    const int wn   = w & 3;           // 0..3: cols wn*64..+63
    const int lr   = lane & 15;
    const int hi   = lane >> 4;

    // XCD-chunked, n-fastest: 4 n-siblings of an m-panel on one XCD -> fp32 A
    // panel fetched from HBM once, siblings L2-hit.
    const int nbn = N >> 8;                       // 4 n-tiles
    const int cpx = gridDim.x >> 3;
    const int lid = (blockIdx.x & 7) * cpx + (blockIdx.x >> 3);
    const int bn0 = (lid % nbn) << 8;
    const int bm0 = (lid / nbn) << 7;             // BM = 128

    const float* Asrc  = Afp + (size_t)bm0 * K;
    const bf16*  Bsrc0 = Bw + (size_t)bn0 * K;
    const bf16*  Bsrc1 = Bw + (size_t)(bn0 + 128) * K;

    f32x4 acc[4][4] = {};
    bf16x8 af[4], bf[4];

    const int x0  = ((hi ^ (lr & 7)) << 4);       // B ks0 slot offset (8 slots/row)
    const int x1  = (((4 + hi) ^ (lr & 7)) << 4); // B ks1
    const int ax0 = x0 << 1;                      // A ks0 (16 slots/row, same XOR <<1)
    const int ax1 = x1 << 1;                      // A ks1

#define RDA_F(AXS) do { \
    _Pragma("unroll") \
    for (int m = 0; m < 4; ++m) { \
        const int _r = (wm << 6) + (m << 4) + lr; \
        const char* _p = As + _r * 256 + (AXS); \
        const f32x4 _u0 = *(const f32x4*)_p; \
        const f32x4 _u1 = *(const f32x4*)(_p + 16); \
        bf16x8 _h; \
        _h[0]=(bf16)_u0[0]; _h[1]=(bf16)_u0[1]; _h[2]=(bf16)_u0[2]; _h[3]=(bf16)_u0[3]; \
        _h[4]=(bf16)_u1[0]; _h[5]=(bf16)_u1[1]; _h[6]=(bf16)_u1[2]; _h[7]=(bf16)_u1[3]; \
        af[m] = _h; \
    } \
} while (0)

#define RDB(XS) do { \
    _Pragma("unroll") \
    for (int n = 0; n < 4; ++n) { \
        const int _r = (wn << 6) + (n << 4) + lr; \
        bf[n] = *(const bf16x8*)(Bs + _r * 128 + (XS)); \
    } \
} while (0)

#define MF16() do { \
    __builtin_amdgcn_s_setprio(1); \
    _Pragma("unroll") \
    for (int m = 0; m < 4; ++m) \
        _Pragma("unroll") \
        for (int n = 0; n < 4; ++n) \
            acc[m][n] = __builtin_amdgcn_mfma_f32_16x16x32_bf16(af[m], bf[n], acc[m][n], 0, 0, 0); \
    __builtin_amdgcn_s_setprio(0); \
} while (0)

#define VMCNT0() asm volatile("s_waitcnt vmcnt(0)" ::: "memory")
#define LGKM0()  asm volatile("s_waitcnt lgkmcnt(0)" ::: "memory")

    // ---------------- prologue: stage tile 0 ----------------
    stage_Afp(Asrc, K, 0, As, t);
    stage_half(Bsrc0, K, 0, Bs, t);
    stage_half(Bsrc1, K, 0, Bs + 16384, t);
    VMCNT0();
    BAR();

    const int NT = K >> 6;   // 16 K-tiles
    for (int kt = 0; kt < NT; ++kt) {
        const bool more = (kt + 1) < NT;

        RDA_F(ax0); RDB(x0);
        MF16();                       // ks0
        RDA_F(ax1); RDB(x1);          // ks1 (cvt VALU overlaps co-block MFMA)
        LGKM0();                      // this wave's LDS reads complete
        BAR();                        // all waves done reading the buffer
        if (more) {
            stage_Afp(Asrc, K, kt + 1, As, t);
            stage_half(Bsrc0, K, kt + 1, Bs, t);
            stage_half(Bsrc1, K, kt + 1, Bs + 16384, t);
        }
        MF16();                       // ks1 on regs; stage DMA flies underneath
        if (more) { VMCNT0(); }       // stage complete (drain overlaps co-block)
        BAR();
    }

    // ---------------- epilogue: alpha * acc + bias ----------------
    const float alpha = *alphap;
    float bv[4];
    #pragma unroll
    for (int nf = 0; nf < 4; ++nf) bv[nf] = bias[bn0 + (wn << 6) + (nf << 4) + lr];

    #pragma unroll
    for (int mf = 0; mf < 4; ++mf) {
        const int grow = bm0 + (wm << 6) + (mf << 4) + (hi << 2);
        #pragma unroll
        for (int nf = 0; nf < 4; ++nf) {
            const int gcol = bn0 + (wn << 6) + (nf << 4) + lr;
            #pragma unroll
            for (int r = 0; r < 4; ++r)
                C[(size_t)(grow + r) * N + gcol] = alpha * acc[mf][nf][r] + bv[nf];
        }
    }
#undef RDA_F
#undef RDB
#undef MF16
#undef VMCNT0
#undef LGKM0
}

// ---------- fallback GEMM (round-1 proven): fp32 A staged in-kernel ----------
__global__ __launch_bounds__(256) void k_gemm_fb(const float* __restrict__ A,
                                                 const bf16* __restrict__ Bw,
                                                 const float* __restrict__ alphap,
                                                 const float* __restrict__ bias,
                                                 float* __restrict__ C,
                                                 int M, int N, int K) {
    __shared__ bf16 As[128 * 32];
    __shared__ bf16 Bs[128 * 32];
    const int t = threadIdx.x, lane = t & 63, wave = t >> 6;
    const int nbm = M >> 7;
    const int bm0 = (blockIdx.x % nbm) << 7;
    const int bn0 = (blockIdx.x / nbm) << 7;
    const int wr = (wave >> 1) << 6, wc = (wave & 1) << 6;
    f32x4 acc[4][4] = {};
    const int lr = lane & 15, lk = (lane >> 4) << 3;
    for (int k0 = 0; k0 < K; k0 += 32) {
        #pragma unroll
        for (int j = 0; j < 2; ++j) {
            const int c = t + j * 256;
            async_load16(Bw + (size_t)(bn0 + (c >> 2)) * K + k0 + ((c & 3) << 3),
                         (char*)Bs + j * 4096 + wave * 1024);
        }
        #pragma unroll
        for (int i = 0; i < 4; ++i) {
            const int idx = t + i * 256;
            const int row = idx >> 3, c4 = (idx & 7) << 2;
            const float4 v = *(const float4*)(A + (size_t)(bm0 + row) * K + k0 + c4);
            bf16x4 h;
            h[0] = (bf16)v.x; h[1] = (bf16)v.y; h[2] = (bf16)v.z; h[3] = (bf16)v.w;
            *(bf16x4*)(As + row * 32 + c4) = h;
        }
        __syncthreads();
        bf16x8 af[4], bfr[4];
        #pragma unroll
        for (int m = 0; m < 4; ++m) af[m] = *(const bf16x8*)(As + (wr + m * 16 + lr) * 32 + lk);
        #pragma unroll
        for (int n = 0; n < 4; ++n) bfr[n] = *(const bf16x8*)(Bs + (wc + n * 16 + lr) * 32 + lk);
        #pragma unroll
        for (int m = 0; m < 4; ++m)
            #pragma unroll
            for (int n = 0; n < 4; ++n)
                acc[m][n] = __builtin_amdgcn_mfma_f32_16x16x32_bf16(af[m], bfr[n], acc[m][n], 0, 0, 0);
        __syncthreads();
    }
    const float alpha = *alphap;
    #pragma unroll
    for (int m = 0; m < 4; ++m)
        #pragma unroll
        for (int n = 0; n < 4; ++n) {
            const int gcol = bn0 + wc + n * 16 + lr;
            const float bv = bias[gcol];
            #pragma unroll
            for (int r = 0; r < 4; ++r) {
                const int grow = bm0 + wr + m * 16 + ((lane >> 4) << 2) + r;
                C[(size_t)grow * N + gcol] = alpha * acc[m][n][r] + bv;
            }
        }
}

extern "C" void kernel_launch(void* const* d_in, const int* in_sizes, int n_in,
                              void* d_out, int out_size, void* d_ws, size_t ws_size,
                              hipStream_t stream) {
    const float* x     = (const float*)d_in[0];
    const float* wgt   = (const float*)d_in[1];
    const float* alpha = (const float*)d_in[2];
    const float* bias  = (const float*)d_in[3];
    float* out = (float*)d_out;

    const int wn   = in_sizes[1];        // 1048576
    const int dout = in_sizes[3];        // 1024
    const int din  = wn / dout;          // 1024
    const int m    = in_sizes[0] / din;  // 32768

    char* ws = (char*)d_ws;
    double* part = (double*)(ws + 64);          // 256 doubles
    bf16*   wt   = (bf16*)(ws + 8192);          // 2 MiB ternary weights

    k_abs_part<<<256, 256, 0, stream>>>(wgt, wn, part);
    k_quantW<<<512, 256, 0, stream>>>(wgt, part, wt, wn / 4, wn);

    const bool useH = (m % 128) == 0 && (dout % 256) == 0 && (din % 64) == 0 &&
                      ((m / 128) * (dout / 256)) % 8 == 0;
    if (useH) {
        dim3 grid((m / 128) * (dout / 256));
        k_gemmH<<<grid, 512, 0, stream>>>(x, wt, alpha, bias, out, m, dout, din);
    } else {
        dim3 grid((m / 128) * (dout / 128));
        k_gemm_fb<<<grid, 256, 0, stream>>>(x, wt, alpha, bias, out, m, dout, din);
    }
}

// Round 11
// 197.201 us; speedup vs baseline: 1.7226x; 1.7226x over previous
//
#include <hip/hip_runtime.h>
#include <hip/hip_bf16.h>

typedef __bf16 bf16;
typedef __attribute__((ext_vector_type(8))) __bf16 bf16x8;
typedef __attribute__((ext_vector_type(4))) __bf16 bf16x4;
typedef __attribute__((ext_vector_type(4))) float f32x4;

#define BAR() __builtin_amdgcn_s_barrier()

__device__ __forceinline__ void async_load16(const void* g, void* l) {
    __builtin_amdgcn_global_load_lds(
        (const __attribute__((address_space(1))) void*)g,
        (__attribute__((address_space(3))) void*)l, 16, 0, 0);
}

// ---------- kernel 1: per-block partial sum of |w| (deterministic tree) ----------
__global__ __launch_bounds__(256) void k_abs_part(const float* __restrict__ w, int n,
                                                  double* __restrict__ part) {
    __shared__ double sd[256];
    const int per_block = n / gridDim.x;
    const int base = blockIdx.x * per_block;
    double s = 0.0;
    for (int i = threadIdx.x; i < per_block; i += 256)
        s += (double)fabsf(w[base + i]);
    sd[threadIdx.x] = s;
    __syncthreads();
    for (int off = 128; off > 0; off >>= 1) {
        if (threadIdx.x < off) sd[threadIdx.x] += sd[threadIdx.x + off];
        __syncthreads();
    }
    if (threadIdx.x == 0) part[blockIdx.x] = sd[0];
}

// ---------- kernel 2: finalize delta locally + quantize W to ternary bf16 ----------
__global__ __launch_bounds__(256) void k_quantW(const float* __restrict__ w,
                                                const double* __restrict__ part,
                                                bf16* __restrict__ wt, int n4, int wn) {
    __shared__ double sd[256];
    sd[threadIdx.x] = part[threadIdx.x];
    __syncthreads();
    for (int off = 128; off > 0; off >>= 1) {
        if (threadIdx.x < off) sd[threadIdx.x] += sd[threadIdx.x + off];
        __syncthreads();
    }
    const float d = (float)(0.7 * sd[0] / (double)wn);
    const int stride = gridDim.x * 256;
    for (int i = blockIdx.x * 256 + threadIdx.x; i < n4; i += stride) {
        const float4 v = ((const float4*)w)[i];
        bf16x4 o;
        o[0] = (bf16)((v.x > d) ? 1.0f : (v.x < -d) ? -1.0f : 0.0f);
        o[1] = (bf16)((v.y > d) ? 1.0f : (v.y < -d) ? -1.0f : 0.0f);
        o[2] = (bf16)((v.z > d) ? 1.0f : (v.z < -d) ? -1.0f : 0.0f);
        o[3] = (bf16)((v.w > d) ? 1.0f : (v.w < -d) ? -1.0f : 0.0f);
        *(bf16x4*)(wt + (size_t)i * 4) = o;
    }
}

// ---------- helper: stage one 128x64 bf16 B-half via global_load_lds, 512 thr ----
// Linear LDS dest; swizzle via inverse-permuted GLOBAL source 16B-slot
// s = (c&7) ^ ((t>>3)&7).  Proven conflict-free (rounds 3-8).
__device__ __forceinline__ void stage_half(const bf16* __restrict__ srch, int K, int kt,
                                           char* dst, int t) {
    #pragma unroll
    for (int r = 0; r < 2; ++r) {
        const int c  = (r << 9) + t;
        const int rp = c >> 3;
        const int s  = (c & 7) ^ ((t >> 3) & 7);
        async_load16(srch + (size_t)rp * K + (kt << 6) + (s << 3), dst + (c << 4));
    }
}

// ---------- helper: stage one 128x64 FP32 A-tile into PADDED LDS rows ----------
// Row = 272B = 16 data slots + 1 pad slot (the pad rotates banks by 1 quad/row:
// bank-quad(r,s) = (r+s) mod 8 -> fragment reads spread 8 lanes/quad, distinct
// addrs — isomorphic to the proven bf16-XOR pattern).  34,816B = 2176 chunks,
// linear dest; chunk c -> row=c/17, slot=c%17; slot 16 = pad (loads row base,
// deterministic garbage, never read).  No swizzle math on either side.
__device__ __forceinline__ void stage_Apad(const float* __restrict__ srch, int K, int kt,
                                           char* dst, int t) {
    #pragma unroll
    for (int r = 0; r < 4; ++r) {
        const int c   = (r << 9) + t;            // 0..2047
        const int row = c / 17;
        const int sl  = c - row * 17;
        const float* src = srch + (size_t)row * K + (kt << 6)
                         + ((sl == 16) ? 0 : (sl << 2));
        async_load16(src, dst + (c << 4));
    }
    if (t < 128) {                                // chunks 2048..2175 (waves 0-1)
        const int c   = 2048 + t;
        const int row = c / 17;
        const int sl  = c - row * 17;
        const float* src = srch + (size_t)row * K + (kt << 6)
                         + ((sl == 16) ? 0 : (sl << 2));
        async_load16(src, dst + (c << 4));
    }
}

// ---------- kernel 3: fused GEMM, A staged as RAW FP32 (padded rows), cvt at read ----
// C[m][n] = alpha * sum_k A[m][k]*Wt[n][k] + bias[n].  BM=128 x BN=256, BK=64,
// 512 thr = 8 waves (2M x 4N), wave tile 64x64.  LDS 66KB (A fp32-padded 34K +
// B bf16 32K) single-buffered -> 2 blocks/CU.  Schedule = round-8 proven 2-phase:
// {RD ks0, MFMA ks0, RD ks1, lgkm0+BAR | stage t+1, MFMA ks1 (regs, hides DMA),
// vmcnt0, BAR}.  fp32->bf16 cvt rides the VALU pipe at fragment read.
__global__ __launch_bounds__(512, 4) void k_gemmP(const float* __restrict__ Afp,
                                                  const bf16* __restrict__ Bw,
                                                  const float* __restrict__ alphap,
                                                  const float* __restrict__ bias,
                                                  float* __restrict__ C,
                                                  int M, int N, int K) {
    __shared__ __align__(16) char As[34816];     // 128 rows x (256B data + 16B pad)
    __shared__ __align__(16) char Bs[32768];     // 256 x 64 bf16, XOR-swizzled

    const int t    = threadIdx.x;
    const int lane = t & 63;
    const int w    = t >> 6;
    const int wm   = w >> 2;          // 0/1: rows wm*64..+63
    const int wn   = w & 3;           // 0..3: cols wn*64..+63
    const int lr   = lane & 15;
    const int hi   = lane >> 4;

    // XCD-chunked, n-fastest: 4 n-siblings of an m-panel on one XCD -> fp32 A
    // panel fetched from HBM once, siblings L2-hit.
    const int nbn = N >> 8;                       // 4 n-tiles
    const int cpx = gridDim.x >> 3;
    const int lid = (blockIdx.x & 7) * cpx + (blockIdx.x >> 3);
    const int bn0 = (lid % nbn) << 8;
    const int bm0 = (lid / nbn) << 7;             // BM = 128

    const float* Asrc  = Afp + (size_t)bm0 * K;
    const bf16*  Bsrc0 = Bw + (size_t)bn0 * K;
    const bf16*  Bsrc1 = Bw + (size_t)(bn0 + 128) * K;

    f32x4 acc[4][4] = {};
    bf16x8 af[4], bf[4];

    const int x0 = ((hi ^ (lr & 7)) << 4);        // B ks0 slot offset
    const int x1 = (((4 + hi) ^ (lr & 7)) << 4);  // B ks1

#define RDA_F(KSOFF) do { \
    _Pragma("unroll") \
    for (int m = 0; m < 4; ++m) { \
        const int _r = (wm << 6) + (m << 4) + lr; \
        const char* _p = As + _r * 272 + (hi << 5) + (KSOFF); \
        const f32x4 _u0 = *(const f32x4*)_p; \
        const f32x4 _u1 = *(const f32x4*)(_p + 16); \
        bf16x8 _h; \
        _h[0]=(bf16)_u0[0]; _h[1]=(bf16)_u0[1]; _h[2]=(bf16)_u0[2]; _h[3]=(bf16)_u0[3]; \
        _h[4]=(bf16)_u1[0]; _h[5]=(bf16)_u1[1]; _h[6]=(bf16)_u1[2]; _h[7]=(bf16)_u1[3]; \
        af[m] = _h; \
    } \
} while (0)

#define RDB(XS) do { \
    _Pragma("unroll") \
    for (int n = 0; n < 4; ++n) { \
        const int _r = (wn << 6) + (n << 4) + lr; \
        bf[n] = *(const bf16x8*)(Bs + _r * 128 + (XS)); \
    } \
} while (0)

#define MF16() do { \
    __builtin_amdgcn_s_setprio(1); \
    _Pragma("unroll") \
    for (int m = 0; m < 4; ++m) \
        _Pragma("unroll") \
        for (int n = 0; n < 4; ++n) \
            acc[m][n] = __builtin_amdgcn_mfma_f32_16x16x32_bf16(af[m], bf[n], acc[m][n], 0, 0, 0); \
    __builtin_amdgcn_s_setprio(0); \
} while (0)

#define VMCNT0() asm volatile("s_waitcnt vmcnt(0)" ::: "memory")
#define LGKM0()  asm volatile("s_waitcnt lgkmcnt(0)" ::: "memory")

    // ---------------- prologue: stage tile 0 ----------------
    stage_Apad(Asrc, K, 0, As, t);
    stage_half(Bsrc0, K, 0, Bs, t);
    stage_half(Bsrc1, K, 0, Bs + 16384, t);
    VMCNT0();
    BAR();

    const int NT = K >> 6;   // 16 K-tiles
    for (int kt = 0; kt < NT; ++kt) {
        const bool more = (kt + 1) < NT;

        RDA_F(0); RDB(x0);
        MF16();                       // ks0
        RDA_F(128); RDB(x1);          // ks1 (cvt VALU overlaps co-block MFMA)
        LGKM0();                      // this wave's LDS reads complete
        BAR();                        // all waves done reading the buffer
        if (more) {
            stage_Apad(Asrc, K, kt + 1, As, t);
            stage_half(Bsrc0, K, kt + 1, Bs, t);
            stage_half(Bsrc1, K, kt + 1, Bs + 16384, t);
        }
        MF16();                       // ks1 on regs; stage DMA flies underneath
        if (more) { VMCNT0(); }       // stage complete (drain overlaps co-block)
        BAR();
    }

    // ---------------- epilogue: alpha * acc + bias ----------------
    const float alpha = *alphap;
    float bv[4];
    #pragma unroll
    for (int nf = 0; nf < 4; ++nf) bv[nf] = bias[bn0 + (wn << 6) + (nf << 4) + lr];

    #pragma unroll
    for (int mf = 0; mf < 4; ++mf) {
        const int grow = bm0 + (wm << 6) + (mf << 4) + (hi << 2);
        #pragma unroll
        for (int nf = 0; nf < 4; ++nf) {
            const int gcol = bn0 + (wn << 6) + (nf << 4) + lr;
            #pragma unroll
            for (int r = 0; r < 4; ++r)
                C[(size_t)(grow + r) * N + gcol] = alpha * acc[mf][nf][r] + bv[nf];
        }
    }
#undef RDA_F
#undef RDB
#undef MF16
#undef VMCNT0
#undef LGKM0
}

// ---------- fallback GEMM (round-1 proven): fp32 A staged in-kernel ----------
__global__ __launch_bounds__(256) void k_gemm_fb(const float* __restrict__ A,
                                                 const bf16* __restrict__ Bw,
                                                 const float* __restrict__ alphap,
                                                 const float* __restrict__ bias,
                                                 float* __restrict__ C,
                                                 int M, int N, int K) {
    __shared__ bf16 As[128 * 32];
    __shared__ bf16 Bs[128 * 32];
    const int t = threadIdx.x, lane = t & 63, wave = t >> 6;
    const int nbm = M >> 7;
    const int bm0 = (blockIdx.x % nbm) << 7;
    const int bn0 = (blockIdx.x / nbm) << 7;
    const int wr = (wave >> 1) << 6, wc = (wave & 1) << 6;
    f32x4 acc[4][4] = {};
    const int lr = lane & 15, lk = (lane >> 4) << 3;
    for (int k0 = 0; k0 < K; k0 += 32) {
        #pragma unroll
        for (int j = 0; j < 2; ++j) {
            const int c = t + j * 256;
            async_load16(Bw + (size_t)(bn0 + (c >> 2)) * K + k0 + ((c & 3) << 3),
                         (char*)Bs + j * 4096 + wave * 1024);
        }
        #pragma unroll
        for (int i = 0; i < 4; ++i) {
            const int idx = t + i * 256;
            const int row = idx >> 3, c4 = (idx & 7) << 2;
            const float4 v = *(const float4*)(A + (size_t)(bm0 + row) * K + k0 + c4);
            bf16x4 h;
            h[0] = (bf16)v.x; h[1] = (bf16)v.y; h[2] = (bf16)v.z; h[3] = (bf16)v.w;
            *(bf16x4*)(As + row * 32 + c4) = h;
        }
        __syncthreads();
        bf16x8 af[4], bfr[4];
        #pragma unroll
        for (int m = 0; m < 4; ++m) af[m] = *(const bf16x8*)(As + (wr + m * 16 + lr) * 32 + lk);
        #pragma unroll
        for (int n = 0; n < 4; ++n) bfr[n] = *(const bf16x8*)(Bs + (wc + n * 16 + lr) * 32 + lk);
        #pragma unroll
        for (int m = 0; m < 4; ++m)
            #pragma unroll
            for (int n = 0; n < 4; ++n)
                acc[m][n] = __builtin_amdgcn_mfma_f32_16x16x32_bf16(af[m], bfr[n], acc[m][n], 0, 0, 0);
        __syncthreads();
    }
    const float alpha = *alphap;
    #pragma unroll
    for (int m = 0; m < 4; ++m)
        #pragma unroll
        for (int n = 0; n < 4; ++n) {
            const int gcol = bn0 + wc + n * 16 + lr;
            const float bv = bias[gcol];
            #pragma unroll
            for (int r = 0; r < 4; ++r) {
                const int grow = bm0 + wr + m * 16 + ((lane >> 4) << 2) + r;
                C[(size_t)grow * N + gcol] = alpha * acc[m][n][r] + bv;
            }
        }
}

extern "C" void kernel_launch(void* const* d_in, const int* in_sizes, int n_in,
                              void* d_out, int out_size, void* d_ws, size_t ws_size,
                              hipStream_t stream) {
    const float* x     = (const float*)d_in[0];
    const float* wgt   = (const float*)d_in[1];
    const float* alpha = (const float*)d_in[2];
    const float* bias  = (const float*)d_in[3];
    float* out = (float*)d_out;

    const int wn   = in_sizes[1];        // 1048576
    const int dout = in_sizes[3];        // 1024
    const int din  = wn / dout;          // 1024
    const int m    = in_sizes[0] / din;  // 32768

    char* ws = (char*)d_ws;
    double* part = (double*)(ws + 64);          // 256 doubles
    bf16*   wt   = (bf16*)(ws + 8192);          // 2 MiB ternary weights

    k_abs_part<<<256, 256, 0, stream>>>(wgt, wn, part);
    k_quantW<<<512, 256, 0, stream>>>(wgt, part, wt, wn / 4, wn);

    const bool useP = (m % 128) == 0 && (dout % 256) == 0 && (din % 64) == 0 &&
                      ((m / 128) * (dout / 256)) % 8 == 0;
    if (useP) {
        dim3 grid((m / 128) * (dout / 256));
        k_gemmP<<<grid, 512, 0, stream>>>(x, wt, alpha, bias, out, m, dout, din);
    } else {
        dim3 grid((m / 128) * (dout / 128));
        k_gemm_fb<<<grid, 256, 0, stream>>>(x, wt, alpha, bias, out, m, dout, din);
    }
}

// Round 12
// 122.778 us; speedup vs baseline: 2.7668x; 1.6062x over previous
//
#include <hip/hip_runtime.h>
#include <hip/hip_bf16.h>

typedef __bf16 bf16;
typedef __attribute__((ext_vector_type(8))) __bf16 bf16x8;
typedef __attribute__((ext_vector_type(4))) __bf16 bf16x4;
typedef __attribute__((ext_vector_type(4))) float f32x4;
typedef __attribute__((ext_vector_type(16))) float f32x16;

#define BAR() __builtin_amdgcn_s_barrier()

__device__ __forceinline__ void async_load16(const void* g, void* l) {
    __builtin_amdgcn_global_load_lds(
        (const __attribute__((address_space(1))) void*)g,
        (__attribute__((address_space(3))) void*)l, 16, 0, 0);
}

// ---------- kernel 1: fused {W |.| partials (blocks 0..255)} + {A fp32->bf16 (rest)} --
__global__ __launch_bounds__(256) void k_absconv(const float* __restrict__ w, int wn,
                                                 double* __restrict__ part,
                                                 const float* __restrict__ x,
                                                 bf16* __restrict__ abf, int na8) {
    if (blockIdx.x < 256) {
        __shared__ double sd[256];
        const int per_block = wn / 256;
        const int base = blockIdx.x * per_block;
        double s = 0.0;
        for (int i = threadIdx.x; i < per_block; i += 256)
            s += (double)fabsf(w[base + i]);
        sd[threadIdx.x] = s;
        __syncthreads();
        for (int off = 128; off > 0; off >>= 1) {
            if (threadIdx.x < off) sd[threadIdx.x] += sd[threadIdx.x + off];
            __syncthreads();
        }
        if (threadIdx.x == 0) part[blockIdx.x] = sd[0];
    } else if (abf != nullptr) {
        const int cb     = blockIdx.x - 256;
        const int stride = (gridDim.x - 256) * 256;
        for (int i = cb * 256 + threadIdx.x; i < na8; i += stride) {
            const float4 a = ((const float4*)x)[2 * i];
            const float4 b = ((const float4*)x)[2 * i + 1];
            bf16x8 h;
            h[0] = (bf16)a.x; h[1] = (bf16)a.y; h[2] = (bf16)a.z; h[3] = (bf16)a.w;
            h[4] = (bf16)b.x; h[5] = (bf16)b.y; h[6] = (bf16)b.z; h[7] = (bf16)b.w;
            ((bf16x8*)abf)[i] = h;
        }
    }
}

// ---------- kernel 2: finalize delta locally + quantize W to ternary bf16 ----------
__global__ __launch_bounds__(256) void k_quantW(const float* __restrict__ w,
                                                const double* __restrict__ part,
                                                bf16* __restrict__ wt, int n4, int wn) {
    __shared__ double sd[256];
    sd[threadIdx.x] = part[threadIdx.x];
    __syncthreads();
    for (int off = 128; off > 0; off >>= 1) {
        if (threadIdx.x < off) sd[threadIdx.x] += sd[threadIdx.x + off];
        __syncthreads();
    }
    const float d = (float)(0.7 * sd[0] / (double)wn);
    const int stride = gridDim.x * 256;
    for (int i = blockIdx.x * 256 + threadIdx.x; i < n4; i += stride) {
        const float4 v = ((const float4*)w)[i];
        bf16x4 o;
        o[0] = (bf16)((v.x > d) ? 1.0f : (v.x < -d) ? -1.0f : 0.0f);
        o[1] = (bf16)((v.y > d) ? 1.0f : (v.y < -d) ? -1.0f : 0.0f);
        o[2] = (bf16)((v.z > d) ? 1.0f : (v.z < -d) ? -1.0f : 0.0f);
        o[3] = (bf16)((v.w > d) ? 1.0f : (v.w < -d) ? -1.0f : 0.0f);
        *(bf16x4*)(wt + (size_t)i * 4) = o;
    }
}

// ---------- helper: stage one 128x64 bf16 half-tile via global_load_lds, 512 thr ----
// Linear LDS dest; swizzle via inverse-permuted GLOBAL source 16B-slot
// s = (c&7) ^ ((t>>3)&7).  Proven conflict-free (rounds 3-8).
__device__ __forceinline__ void stage_half(const bf16* __restrict__ srch, int K, int kt,
                                           char* dst, int t) {
    #pragma unroll
    for (int r = 0; r < 2; ++r) {
        const int c  = (r << 9) + t;
        const int rp = c >> 3;
        const int s  = (c & 7) ^ ((t >> 3) & 7);
        async_load16(srch + (size_t)rp * K + (kt << 6) + (s << 3), dst + (c << 4));
    }
}

// ---------- kernel 3: r8 skeleton with 32x32x16 MFMA ----------
// C[m][n] = alpha * sum_k A[m][k]*Wt[n][k] + bias[n].  BM=128 x BN=256, BK=64,
// 512 thr = 8 waves (2M x 4N), wave tile 64x64 as 2x2 of 32x32 (acc 64 f32).
// LDS 48KB single-buffered -> 2 blocks/CU.  Schedule identical to round 8:
// {RD ks0,ks1; MF ks0; MF ks1; RD ks2,ks3; lgkm0+BAR; stage t+1; MF ks2; MF ks3;
// vmcnt0; BAR}.  32x32x16 layouts: A/B lane l -> row/col l&31, k=8*(l>>5)+j;
// C/D col=lane&31, row=(reg&3)+8*(reg>>2)+4*(lane>>5).
__global__ __launch_bounds__(512, 4) void k_gemm32(const bf16* __restrict__ A,
                                                   const bf16* __restrict__ Bw,
                                                   const float* __restrict__ alphap,
                                                   const float* __restrict__ bias,
                                                   float* __restrict__ C,
                                                   int M, int N, int K) {
    __shared__ __align__(16) char As[16384];    // 128 x 64 bf16, swizzled
    __shared__ __align__(16) char Bs[32768];    // 256 x 64 bf16, swizzled

    const int t    = threadIdx.x;
    const int lane = t & 63;
    const int w    = t >> 6;
    const int wm   = w >> 2;          // 0/1: rows wm*64..+63
    const int wn   = w & 3;           // 0..3: cols wn*64..+63
    const int l31  = lane & 31;
    const int h2   = lane >> 5;       // 0/1: k-half within 16-k step

    // XCD-chunked, n-fastest: XCD owns contiguous m-panels; A L2/L3-reused 4x.
    const int nbn = N >> 8;                       // 4 n-tiles
    const int cpx = gridDim.x >> 3;
    const int lid = (blockIdx.x & 7) * cpx + (blockIdx.x >> 3);
    const int bn0 = (lid % nbn) << 8;
    const int bm0 = (lid / nbn) << 7;             // BM = 128

    const bf16* Asrc  = A  + (size_t)bm0 * K;
    const bf16* Bsrc0 = Bw + (size_t)bn0 * K;
    const bf16* Bsrc1 = Bw + (size_t)(bn0 + 128) * K;

    f32x16 acc[2][2] = {};
    bf16x8 afA[2], bfA[2], afB[2], bfB[2];

#define RD2(KS, AF, BF) do { \
    _Pragma("unroll") \
    for (int mi = 0; mi < 2; ++mi) { \
        const int _r = (wm << 6) + (mi << 5) + l31; \
        const int _s = (((KS) << 1) + h2) ^ (_r & 7); \
        AF[mi] = *(const bf16x8*)(As + _r * 128 + (_s << 4)); \
    } \
    _Pragma("unroll") \
    for (int ni = 0; ni < 2; ++ni) { \
        const int _r = (wn << 6) + (ni << 5) + l31; \
        const int _s = (((KS) << 1) + h2) ^ (_r & 7); \
        BF[ni] = *(const bf16x8*)(Bs + _r * 128 + (_s << 4)); \
    } \
} while (0)

#define MF32(AF, BF) do { \
    __builtin_amdgcn_s_setprio(1); \
    acc[0][0] = __builtin_amdgcn_mfma_f32_32x32x16_bf16(AF[0], BF[0], acc[0][0], 0, 0, 0); \
    acc[0][1] = __builtin_amdgcn_mfma_f32_32x32x16_bf16(AF[0], BF[1], acc[0][1], 0, 0, 0); \
    acc[1][0] = __builtin_amdgcn_mfma_f32_32x32x16_bf16(AF[1], BF[0], acc[1][0], 0, 0, 0); \
    acc[1][1] = __builtin_amdgcn_mfma_f32_32x32x16_bf16(AF[1], BF[1], acc[1][1], 0, 0, 0); \
    __builtin_amdgcn_s_setprio(0); \
} while (0)

#define VMCNT0() asm volatile("s_waitcnt vmcnt(0)" ::: "memory")
#define LGKM0()  asm volatile("s_waitcnt lgkmcnt(0)" ::: "memory")

    // ---------------- prologue: stage tile 0 ----------------
    stage_half(Asrc,  K, 0, As, t);
    stage_half(Bsrc0, K, 0, Bs, t);
    stage_half(Bsrc1, K, 0, Bs + 16384, t);
    VMCNT0();
    BAR();

    const int NT = K >> 6;   // 16 K-tiles, 4 k-steps of 16 each
    for (int kt = 0; kt < NT; ++kt) {
        const bool more = (kt + 1) < NT;

        RD2(0, afA, bfA); RD2(1, afB, bfB);
        MF32(afA, bfA);               // ks0
        MF32(afB, bfB);               // ks1
        RD2(2, afA, bfA); RD2(3, afB, bfB);
        LGKM0();                      // all this wave's LDS reads complete
        BAR();                        // all waves done reading the buffer
        if (more) {
            stage_half(Asrc,  K, kt + 1, As, t);
            stage_half(Bsrc0, K, kt + 1, Bs, t);
            stage_half(Bsrc1, K, kt + 1, Bs + 16384, t);
        }
        MF32(afA, bfA);               // ks2 on regs; stage DMA flies underneath
        MF32(afB, bfB);               // ks3
        if (more) { VMCNT0(); }       // stage complete (drain overlaps co-block)
        BAR();
    }

    // ---------------- epilogue: alpha * acc + bias ----------------
    const float alpha = *alphap;
    #pragma unroll
    for (int ni = 0; ni < 2; ++ni) {
        const int gcol = bn0 + (wn << 6) + (ni << 5) + l31;
        const float bv = bias[gcol];
        #pragma unroll
        for (int mi = 0; mi < 2; ++mi) {
            #pragma unroll
            for (int r = 0; r < 16; ++r) {
                const int grow = bm0 + (wm << 6) + (mi << 5)
                               + (r & 3) + ((r >> 2) << 3) + (h2 << 2);
                C[(size_t)grow * N + gcol] = alpha * acc[mi][ni][r] + bv;
            }
        }
    }
#undef RD2
#undef MF32
#undef VMCNT0
#undef LGKM0
}

// ---------- fallback GEMM (round-1 proven): fp32 A staged in-kernel ----------
__global__ __launch_bounds__(256) void k_gemm_fb(const float* __restrict__ A,
                                                 const bf16* __restrict__ Bw,
                                                 const float* __restrict__ alphap,
                                                 const float* __restrict__ bias,
                                                 float* __restrict__ C,
                                                 int M, int N, int K) {
    __shared__ bf16 As[128 * 32];
    __shared__ bf16 Bs[128 * 32];
    const int t = threadIdx.x, lane = t & 63, wave = t >> 6;
    const int nbm = M >> 7;
    const int bm0 = (blockIdx.x % nbm) << 7;
    const int bn0 = (blockIdx.x / nbm) << 7;
    const int wr = (wave >> 1) << 6, wc = (wave & 1) << 6;
    f32x4 acc[4][4] = {};
    const int lr = lane & 15, lk = (lane >> 4) << 3;
    for (int k0 = 0; k0 < K; k0 += 32) {
        #pragma unroll
        for (int j = 0; j < 2; ++j) {
            const int c = t + j * 256;
            async_load16(Bw + (size_t)(bn0 + (c >> 2)) * K + k0 + ((c & 3) << 3),
                         (char*)Bs + j * 4096 + wave * 1024);
        }
        #pragma unroll
        for (int i = 0; i < 4; ++i) {
            const int idx = t + i * 256;
            const int row = idx >> 3, c4 = (idx & 7) << 2;
            const float4 v = *(const float4*)(A + (size_t)(bm0 + row) * K + k0 + c4);
            bf16x4 h;
            h[0] = (bf16)v.x; h[1] = (bf16)v.y; h[2] = (bf16)v.z; h[3] = (bf16)v.w;
            *(bf16x4*)(As + row * 32 + c4) = h;
        }
        __syncthreads();
        bf16x8 af[4], bfr[4];
        #pragma unroll
        for (int m = 0; m < 4; ++m) af[m] = *(const bf16x8*)(As + (wr + m * 16 + lr) * 32 + lk);
        #pragma unroll
        for (int n = 0; n < 4; ++n) bfr[n] = *(const bf16x8*)(Bs + (wc + n * 16 + lr) * 32 + lk);
        #pragma unroll
        for (int m = 0; m < 4; ++m)
            #pragma unroll
            for (int n = 0; n < 4; ++n)
                acc[m][n] = __builtin_amdgcn_mfma_f32_16x16x32_bf16(af[m], bfr[n], acc[m][n], 0, 0, 0);
        __syncthreads();
    }
    const float alpha = *alphap;
    #pragma unroll
    for (int m = 0; m < 4; ++m)
        #pragma unroll
        for (int n = 0; n < 4; ++n) {
            const int gcol = bn0 + wc + n * 16 + lr;
            const float bv = bias[gcol];
            #pragma unroll
            for (int r = 0; r < 4; ++r) {
                const int grow = bm0 + wr + m * 16 + ((lane >> 4) << 2) + r;
                C[(size_t)grow * N + gcol] = alpha * acc[m][n][r] + bv;
            }
        }
}

extern "C" void kernel_launch(void* const* d_in, const int* in_sizes, int n_in,
                              void* d_out, int out_size, void* d_ws, size_t ws_size,
                              hipStream_t stream) {
    const float* x     = (const float*)d_in[0];
    const float* wgt   = (const float*)d_in[1];
    const float* alpha = (const float*)d_in[2];
    const float* bias  = (const float*)d_in[3];
    float* out = (float*)d_out;

    const int wn   = in_sizes[1];        // 1048576
    const int dout = in_sizes[3];        // 1024
    const int din  = wn / dout;          // 1024
    const int m    = in_sizes[0] / din;  // 32768

    char* ws = (char*)d_ws;
    double* part = (double*)(ws + 64);          // 256 doubles
    bf16*   wt   = (bf16*)(ws + 8192);          // 2 MiB ternary weights
    bf16*   abf  = (bf16*)(ws + (4u << 20));    // 64 MiB bf16 A

    const size_t need = (4u << 20) + (size_t)in_sizes[0] * 2;
    const bool use32 = (ws_size >= need) && (m % 128) == 0 && (dout % 256) == 0 &&
                       (din % 64) == 0 && ((m / 128) * (dout / 256)) % 8 == 0;

    if (use32) {
        k_absconv<<<2304, 256, 0, stream>>>(wgt, wn, part, x, abf, in_sizes[0] / 8);
        k_quantW<<<512, 256, 0, stream>>>(wgt, part, wt, wn / 4, wn);
        dim3 grid((m / 128) * (dout / 256));
        k_gemm32<<<grid, 512, 0, stream>>>(abf, wt, alpha, bias, out, m, dout, din);
    } else {
        k_absconv<<<256, 256, 0, stream>>>(wgt, wn, part, x, nullptr, 0);
        k_quantW<<<512, 256, 0, stream>>>(wgt, part, wt, wn / 4, wn);
        dim3 grid((m / 128) * (dout / 128));
        k_gemm_fb<<<grid, 256, 0, stream>>>(x, wt, alpha, bias, out, m, dout, din);
    }
}

// Round 13
// 119.604 us; speedup vs baseline: 2.8402x; 1.0265x over previous
//
#include <hip/hip_runtime.h>
#include <hip/hip_bf16.h>

typedef __bf16 bf16;
typedef __attribute__((ext_vector_type(8))) __bf16 bf16x8;
typedef __attribute__((ext_vector_type(4))) __bf16 bf16x4;
typedef __attribute__((ext_vector_type(4))) float f32x4;

#define BAR() __builtin_amdgcn_s_barrier()

__device__ __forceinline__ void async_load16(const void* g, void* l) {
    __builtin_amdgcn_global_load_lds(
        (const __attribute__((address_space(1))) void*)g,
        (__attribute__((address_space(3))) void*)l, 16, 0, 0);
}

// ---------- kernel 1: per-block partial sum of |w| (deterministic tree) ----------
__global__ __launch_bounds__(256) void k_abs_part(const float* __restrict__ w, int n,
                                                  double* __restrict__ part) {
    __shared__ double sd[256];
    const int per_block = n / gridDim.x;
    const int base = blockIdx.x * per_block;
    double s = 0.0;
    for (int i = threadIdx.x; i < per_block; i += 256)
        s += (double)fabsf(w[base + i]);
    sd[threadIdx.x] = s;
    __syncthreads();
    for (int off = 128; off > 0; off >>= 1) {
        if (threadIdx.x < off) sd[threadIdx.x] += sd[threadIdx.x + off];
        __syncthreads();
    }
    if (threadIdx.x == 0) part[blockIdx.x] = sd[0];
}

// ---------- kernel 2: fused {delta finalize + W quantize} || {A fp32->bf16} ----------
// Every block re-reduces the 256 partials (2 KB, L2-hot, deterministic order) to get
// delta locally.  Blocks [0,qb) quantize W; blocks [qb,grid) stream-convert A.
// W-quantize thus runs in parallel with the (longer) A-convert instead of serial.
__global__ __launch_bounds__(256) void k_quant_conv(const float* __restrict__ w,
                                                    const double* __restrict__ part,
                                                    bf16* __restrict__ wt, int n4,
                                                    const float* __restrict__ x,
                                                    bf16* __restrict__ abf, int na8,
                                                    int wn, int qb) {
    __shared__ double sd[256];
    sd[threadIdx.x] = part[threadIdx.x];
    __syncthreads();
    for (int off = 128; off > 0; off >>= 1) {
        if (threadIdx.x < off) sd[threadIdx.x] += sd[threadIdx.x + off];
        __syncthreads();
    }
    const float d = (float)(0.7 * sd[0] / (double)wn);

    if (blockIdx.x < qb) {
        const int stride = qb * 256;
        for (int i = blockIdx.x * 256 + threadIdx.x; i < n4; i += stride) {
            const float4 v = ((const float4*)w)[i];
            bf16x4 o;
            o[0] = (bf16)((v.x > d) ? 1.0f : (v.x < -d) ? -1.0f : 0.0f);
            o[1] = (bf16)((v.y > d) ? 1.0f : (v.y < -d) ? -1.0f : 0.0f);
            o[2] = (bf16)((v.z > d) ? 1.0f : (v.z < -d) ? -1.0f : 0.0f);
            o[3] = (bf16)((v.w > d) ? 1.0f : (v.w < -d) ? -1.0f : 0.0f);
            *(bf16x4*)(wt + (size_t)i * 4) = o;
        }
    } else if (abf != nullptr) {
        const int cb     = blockIdx.x - qb;
        const int stride = (gridDim.x - qb) * 256;
        for (int i = cb * 256 + threadIdx.x; i < na8; i += stride) {
            const float4 a = ((const float4*)x)[2 * i];
            const float4 b = ((const float4*)x)[2 * i + 1];
            bf16x8 h;
            h[0] = (bf16)a.x; h[1] = (bf16)a.y; h[2] = (bf16)a.z; h[3] = (bf16)a.w;
            h[4] = (bf16)b.x; h[5] = (bf16)b.y; h[6] = (bf16)b.z; h[7] = (bf16)b.w;
            ((bf16x8*)abf)[i] = h;
        }
    }
}

// ---------- helper: stage one 128x64 bf16 half-tile via global_load_lds, 512 thr ----
// Linear LDS dest; swizzle via inverse-permuted GLOBAL source 16B-slot
// s = (c&7) ^ ((t>>3)&7).  Proven conflict-free (rounds 3-8).
__device__ __forceinline__ void stage_half(const bf16* __restrict__ srch, int K, int kt,
                                           char* dst, int t) {
    #pragma unroll
    for (int r = 0; r < 2; ++r) {
        const int c  = (r << 9) + t;
        const int rp = c >> 3;
        const int s  = (c & 7) ^ ((t >> 3) & 7);
        async_load16(srch + (size_t)rp * K + (kt << 6) + (s << 3), dst + (c << 4));
    }
}

// ---------- kernel 3: 128x256 tile, 2-phase, single-buffer, 2 blocks/CU ----------
// (round-8 proven: ~73us, MfmaUtil>34%, conflicts 0).  C[m][n] = alpha * sum_k
// A[m][k]*Wt[n][k] + bias[n].  512 thr = 8 waves (2M x 4N), wave tile 64x64,
// 16x16x32 MFMA (the only verified conflict-free fragment pattern), LDS 48KB,
// BK=64.  Per K-tile: rd ks0 -> MFMA ks0 -> rd ks1 -> lgkm0+BAR -> stage t+1 ->
// MFMA ks1 (regs, hides DMA) -> vmcnt0+BAR.  Drains overlap the co-resident
// block; 2 generations stagger C-writes under compute.
__global__ __launch_bounds__(512, 4) void k_gemm2(const bf16* __restrict__ A,
                                                  const bf16* __restrict__ Bw,
                                                  const float* __restrict__ alphap,
                                                  const float* __restrict__ bias,
                                                  float* __restrict__ C,
                                                  int M, int N, int K) {
    __shared__ __align__(16) char As[16384];    // 128 x 64 bf16, swizzled
    __shared__ __align__(16) char Bs[32768];    // 256 x 64 bf16, swizzled

    const int t    = threadIdx.x;
    const int lane = t & 63;
    const int w    = t >> 6;
    const int wm   = w >> 2;          // 0/1: rows wm*64..+63
    const int wn   = w & 3;           // 0..3: cols wn*64..+63
    const int lr   = lane & 15;
    const int hi   = lane >> 4;

    // XCD-chunked, n-fastest: XCD owns contiguous m-panels; A L2/L3-reused 4x.
    const int nbn = N >> 8;                       // 4 n-tiles
    const int cpx = gridDim.x >> 3;
    const int lid = (blockIdx.x & 7) * cpx + (blockIdx.x >> 3);
    const int bn0 = (lid % nbn) << 8;
    const int bm0 = (lid / nbn) << 7;             // BM = 128

    const bf16* Asrc  = A  + (size_t)bm0 * K;
    const bf16* Bsrc0 = Bw + (size_t)bn0 * K;
    const bf16* Bsrc1 = Bw + (size_t)(bn0 + 128) * K;

    f32x4 acc[4][4] = {};
    bf16x8 af[4], bf[4];

    const int x0 = ((hi ^ (lr & 7)) << 4);        // ks0 swizzled slot offset
    const int x1 = (((4 + hi) ^ (lr & 7)) << 4);  // ks1

#define RDA(XS) do { \
    _Pragma("unroll") \
    for (int m = 0; m < 4; ++m) { \
        const int _r = (wm << 6) + (m << 4) + lr; \
        af[m] = *(const bf16x8*)(As + _r * 128 + (XS)); \
    } \
} while (0)

#define RDB(XS) do { \
    _Pragma("unroll") \
    for (int n = 0; n < 4; ++n) { \
        const int _r = (wn << 6) + (n << 4) + lr; \
        bf[n] = *(const bf16x8*)(Bs + _r * 128 + (XS)); \
    } \
} while (0)

#define MF16() do { \
    __builtin_amdgcn_s_setprio(1); \
    _Pragma("unroll") \
    for (int m = 0; m < 4; ++m) \
        _Pragma("unroll") \
        for (int n = 0; n < 4; ++n) \
            acc[m][n] = __builtin_amdgcn_mfma_f32_16x16x32_bf16(af[m], bf[n], acc[m][n], 0, 0, 0); \
    __builtin_amdgcn_s_setprio(0); \
} while (0)

#define VMCNT0() asm volatile("s_waitcnt vmcnt(0)" ::: "memory")
#define LGKM0()  asm volatile("s_waitcnt lgkmcnt(0)" ::: "memory")

    // ---------------- prologue: stage tile 0 ----------------
    stage_half(Asrc,  K, 0, As, t);
    stage_half(Bsrc0, K, 0, Bs, t);
    stage_half(Bsrc1, K, 0, Bs + 16384, t);
    VMCNT0();
    BAR();

    const int NT = K >> 6;   // 16 K-tiles
    for (int kt = 0; kt < NT; ++kt) {
        const bool more = (kt + 1) < NT;

        RDA(x0); RDB(x0);
        MF16();                       // ks0 (LDS latency hidden by 4 waves/SIMD)
        RDA(x1); RDB(x1);             // ks1 into same regs (ks0 frags dead)
        LGKM0();                      // all this wave's LDS reads complete
        BAR();                        // all waves done reading the buffer
        if (more) {
            stage_half(Asrc,  K, kt + 1, As, t);
            stage_half(Bsrc0, K, kt + 1, Bs, t);
            stage_half(Bsrc1, K, kt + 1, Bs + 16384, t);
        }
        MF16();                       // ks1 on regs; stage DMA flies underneath
        if (more) { VMCNT0(); }       // stage complete (drain overlaps co-block)
        BAR();
    }

    // ---------------- epilogue: alpha * acc + bias ----------------
    const float alpha = *alphap;
    float bv[4];
    #pragma unroll
    for (int nf = 0; nf < 4; ++nf) bv[nf] = bias[bn0 + (wn << 6) + (nf << 4) + lr];

    #pragma unroll
    for (int mf = 0; mf < 4; ++mf) {
        const int grow = bm0 + (wm << 6) + (mf << 4) + (hi << 2);
        #pragma unroll
        for (int nf = 0; nf < 4; ++nf) {
            const int gcol = bn0 + (wn << 6) + (nf << 4) + lr;
            #pragma unroll
            for (int r = 0; r < 4; ++r)
                C[(size_t)(grow + r) * N + gcol] = alpha * acc[mf][nf][r] + bv[nf];
        }
    }
#undef RDA
#undef RDB
#undef MF16
#undef VMCNT0
#undef LGKM0
}

// ---------- fallback GEMM (round-1 proven): fp32 A staged in-kernel ----------
__global__ __launch_bounds__(256) void k_gemm_fb(const float* __restrict__ A,
                                                 const bf16* __restrict__ Bw,
                                                 const float* __restrict__ alphap,
                                                 const float* __restrict__ bias,
                                                 float* __restrict__ C,
                                                 int M, int N, int K) {
    __shared__ bf16 As[128 * 32];
    __shared__ bf16 Bs[128 * 32];
    const int t = threadIdx.x, lane = t & 63, wave = t >> 6;
    const int nbm = M >> 7;
    const int bm0 = (blockIdx.x % nbm) << 7;
    const int bn0 = (blockIdx.x / nbm) << 7;
    const int wr = (wave >> 1) << 6, wc = (wave & 1) << 6;
    f32x4 acc[4][4] = {};
    const int lr = lane & 15, lk = (lane >> 4) << 3;
    for (int k0 = 0; k0 < K; k0 += 32) {
        #pragma unroll
        for (int j = 0; j < 2; ++j) {
            const int c = t + j * 256;
            async_load16(Bw + (size_t)(bn0 + (c >> 2)) * K + k0 + ((c & 3) << 3),
                         (char*)Bs + j * 4096 + wave * 1024);
        }
        #pragma unroll
        for (int i = 0; i < 4; ++i) {
            const int idx = t + i * 256;
            const int row = idx >> 3, c4 = (idx & 7) << 2;
            const float4 v = *(const float4*)(A + (size_t)(bm0 + row) * K + k0 + c4);
            bf16x4 h;
            h[0] = (bf16)v.x; h[1] = (bf16)v.y; h[2] = (bf16)v.z; h[3] = (bf16)v.w;
            *(bf16x4*)(As + row * 32 + c4) = h;
        }
        __syncthreads();
        bf16x8 af[4], bfr[4];
        #pragma unroll
        for (int m = 0; m < 4; ++m) af[m] = *(const bf16x8*)(As + (wr + m * 16 + lr) * 32 + lk);
        #pragma unroll
        for (int n = 0; n < 4; ++n) bfr[n] = *(const bf16x8*)(Bs + (wc + n * 16 + lr) * 32 + lk);
        #pragma unroll
        for (int m = 0; m < 4; ++m)
            #pragma unroll
            for (int n = 0; n < 4; ++n)
                acc[m][n] = __builtin_amdgcn_mfma_f32_16x16x32_bf16(af[m], bfr[n], acc[m][n], 0, 0, 0);
        __syncthreads();
    }
    const float alpha = *alphap;
    #pragma unroll
    for (int m = 0; m < 4; ++m)
        #pragma unroll
        for (int n = 0; n < 4; ++n) {
            const int gcol = bn0 + wc + n * 16 + lr;
            const float bv = bias[gcol];
            #pragma unroll
            for (int r = 0; r < 4; ++r) {
                const int grow = bm0 + wr + m * 16 + ((lane >> 4) << 2) + r;
                C[(size_t)grow * N + gcol] = alpha * acc[m][n][r] + bv;
            }
        }
}

extern "C" void kernel_launch(void* const* d_in, const int* in_sizes, int n_in,
                              void* d_out, int out_size, void* d_ws, size_t ws_size,
                              hipStream_t stream) {
    const float* x     = (const float*)d_in[0];
    const float* wgt   = (const float*)d_in[1];
    const float* alpha = (const float*)d_in[2];
    const float* bias  = (const float*)d_in[3];
    float* out = (float*)d_out;

    const int wn   = in_sizes[1];        // 1048576
    const int dout = in_sizes[3];        // 1024
    const int din  = wn / dout;          // 1024
    const int m    = in_sizes[0] / din;  // 32768

    char* ws = (char*)d_ws;
    double* part = (double*)(ws + 64);          // 256 doubles
    bf16*   wt   = (bf16*)(ws + 8192);          // 2 MiB ternary weights
    bf16*   abf  = (bf16*)(ws + (4u << 20));    // 64 MiB bf16 A

    const size_t need = (4u << 20) + (size_t)in_sizes[0] * 2;
    const bool use2 = (ws_size >= need) && (m % 128) == 0 && (dout % 256) == 0 &&
                      (din % 64) == 0 && ((m / 128) * (dout / 256)) % 8 == 0;

    k_abs_part<<<256, 256, 0, stream>>>(wgt, wn, part);

    if (use2) {
        // blocks [0,512): quantize W (parallel with) [512,2560): convert A
        k_quant_conv<<<2560, 256, 0, stream>>>(wgt, part, wt, wn / 4,
                                               x, abf, in_sizes[0] / 8, wn, 512);
        dim3 grid((m / 128) * (dout / 256));
        k_gemm2<<<grid, 512, 0, stream>>>(abf, wt, alpha, bias, out, m, dout, din);
    } else {
        k_quant_conv<<<512, 256, 0, stream>>>(wgt, part, wt, wn / 4,
                                              nullptr, nullptr, 0, wn, 512);
        dim3 grid((m / 128) * (dout / 128));
        k_gemm_fb<<<grid, 256, 0, stream>>>(x, wt, alpha, bias, out, m, dout, din);
    }
}

// Round 14
// 115.663 us; speedup vs baseline: 2.9370x; 1.0341x over previous
//
#include <hip/hip_runtime.h>
#include <hip/hip_bf16.h>

typedef __bf16 bf16;
typedef __attribute__((ext_vector_type(8))) __bf16 bf16x8;
typedef __attribute__((ext_vector_type(4))) __bf16 bf16x4;
typedef __attribute__((ext_vector_type(4))) float f32x4;

#define BAR() __builtin_amdgcn_s_barrier()

__device__ __forceinline__ void async_load16(const void* g, void* l) {
    __builtin_amdgcn_global_load_lds(
        (const __attribute__((address_space(1))) void*)g,
        (__attribute__((address_space(3))) void*)l, 16, 0, 0);
}

// ---------- kernel 1: fused {W |.| partials (blocks 0..255)} + {A fp32->bf16 (rest)} --
// A-convert is independent of delta, so it runs in parallel with the W reduction.
// Blocks 0..255 produce deterministic partials (fixed 256-block tree, same every call).
__global__ __launch_bounds__(256) void k_absconv(const float* __restrict__ w, int wn,
                                                 double* __restrict__ part,
                                                 const float* __restrict__ x,
                                                 bf16* __restrict__ abf, int na8) {
    if (blockIdx.x < 256) {
        __shared__ double sd[256];
        const int per_block = wn / 256;
        const int base = blockIdx.x * per_block;
        double s = 0.0;
        for (int i = threadIdx.x; i < per_block; i += 256)
            s += (double)fabsf(w[base + i]);
        sd[threadIdx.x] = s;
        __syncthreads();
        for (int off = 128; off > 0; off >>= 1) {
            if (threadIdx.x < off) sd[threadIdx.x] += sd[threadIdx.x + off];
            __syncthreads();
        }
        if (threadIdx.x == 0) part[blockIdx.x] = sd[0];
    } else if (abf != nullptr) {
        const int cb     = blockIdx.x - 256;
        const int stride = (gridDim.x - 256) * 256;
        for (int i = cb * 256 + threadIdx.x; i < na8; i += stride) {
            const float4 a = ((const float4*)x)[2 * i];
            const float4 b = ((const float4*)x)[2 * i + 1];
            bf16x8 h;
            h[0] = (bf16)a.x; h[1] = (bf16)a.y; h[2] = (bf16)a.z; h[3] = (bf16)a.w;
            h[4] = (bf16)b.x; h[5] = (bf16)b.y; h[6] = (bf16)b.z; h[7] = (bf16)b.w;
            ((bf16x8*)abf)[i] = h;
        }
    }
}

// ---------- kernel 2: finalize delta locally + quantize W to ternary bf16 ----------
__global__ __launch_bounds__(256) void k_quantW(const float* __restrict__ w,
                                                const double* __restrict__ part,
                                                bf16* __restrict__ wt, int n4, int wn) {
    __shared__ double sd[256];
    sd[threadIdx.x] = part[threadIdx.x];
    __syncthreads();
    for (int off = 128; off > 0; off >>= 1) {
        if (threadIdx.x < off) sd[threadIdx.x] += sd[threadIdx.x + off];
        __syncthreads();
    }
    const float d = (float)(0.7 * sd[0] / (double)wn);
    const int stride = gridDim.x * 256;
    for (int i = blockIdx.x * 256 + threadIdx.x; i < n4; i += stride) {
        const float4 v = ((const float4*)w)[i];
        bf16x4 o;
        o[0] = (bf16)((v.x > d) ? 1.0f : (v.x < -d) ? -1.0f : 0.0f);
        o[1] = (bf16)((v.y > d) ? 1.0f : (v.y < -d) ? -1.0f : 0.0f);
        o[2] = (bf16)((v.z > d) ? 1.0f : (v.z < -d) ? -1.0f : 0.0f);
        o[3] = (bf16)((v.w > d) ? 1.0f : (v.w < -d) ? -1.0f : 0.0f);
        *(bf16x4*)(wt + (size_t)i * 4) = o;
    }
}

// ---------- helper: stage one 128x64 bf16 half-tile via global_load_lds, 512 thr ----
// Linear LDS dest (gload_lds requirement); swizzle via inverse-permuted GLOBAL
// source 16B-slot s = (c&7) ^ ((t>>3)&7).  Proven conflict-free (rounds 3-8).
__device__ __forceinline__ void stage_half(const bf16* __restrict__ srch, int K, int kt,
                                           char* dst, int t) {
    #pragma unroll
    for (int r = 0; r < 2; ++r) {
        const int c  = (r << 9) + t;
        const int rp = c >> 3;
        const int s  = (c & 7) ^ ((t >> 3) & 7);
        async_load16(srch + (size_t)rp * K + (kt << 6) + (s << 3), dst + (c << 4));
    }
}

// ---------- kernel 3: 128x256 tile, 2-phase, single-buffer, 2 blocks/CU ----------
// (round-8 proven best: ~73us, conflicts 0).  C[m][n] = alpha * sum_k
// A[m][k]*Wt[n][k] + bias[n].  512 thr = 8 waves (2M x 4N), wave tile 64x64,
// 16x16x32 MFMA (the only verified conflict-free fragment pattern), LDS 48KB,
// BK=64.  Per K-tile: rd ks0 -> MFMA ks0 -> rd ks1 -> lgkm0+BAR -> stage t+1 ->
// MFMA ks1 (regs, hides DMA) -> vmcnt0+BAR.  Drains overlap the co-resident
// block; 2 block-generations stagger C-writes under compute.
__global__ __launch_bounds__(512, 4) void k_gemm2(const bf16* __restrict__ A,
                                                  const bf16* __restrict__ Bw,
                                                  const float* __restrict__ alphap,
                                                  const float* __restrict__ bias,
                                                  float* __restrict__ C,
                                                  int M, int N, int K) {
    __shared__ __align__(16) char As[16384];    // 128 x 64 bf16, swizzled
    __shared__ __align__(16) char Bs[32768];    // 256 x 64 bf16, swizzled

    const int t    = threadIdx.x;
    const int lane = t & 63;
    const int w    = t >> 6;
    const int wm   = w >> 2;          // 0/1: rows wm*64..+63
    const int wn   = w & 3;           // 0..3: cols wn*64..+63
    const int lr   = lane & 15;
    const int hi   = lane >> 4;

    // XCD-chunked, n-fastest: XCD owns contiguous m-panels; A L2/L3-reused 4x.
    const int nbn = N >> 8;                       // 4 n-tiles
    const int cpx = gridDim.x >> 3;
    const int lid = (blockIdx.x & 7) * cpx + (blockIdx.x >> 3);
    const int bn0 = (lid % nbn) << 8;
    const int bm0 = (lid / nbn) << 7;             // BM = 128

    const bf16* Asrc  = A  + (size_t)bm0 * K;
    const bf16* Bsrc0 = Bw + (size_t)bn0 * K;
    const bf16* Bsrc1 = Bw + (size_t)(bn0 + 128) * K;

    f32x4 acc[4][4] = {};
    bf16x8 af[4], bf[4];

    const int x0 = ((hi ^ (lr & 7)) << 4);        // ks0 swizzled slot offset
    const int x1 = (((4 + hi) ^ (lr & 7)) << 4);  // ks1

#define RDA(XS) do { \
    _Pragma("unroll") \
    for (int m = 0; m < 4; ++m) { \
        const int _r = (wm << 6) + (m << 4) + lr; \
        af[m] = *(const bf16x8*)(As + _r * 128 + (XS)); \
    } \
} while (0)

#define RDB(XS) do { \
    _Pragma("unroll") \
    for (int n = 0; n < 4; ++n) { \
        const int _r = (wn << 6) + (n << 4) + lr; \
        bf[n] = *(const bf16x8*)(Bs + _r * 128 + (XS)); \
    } \
} while (0)

#define MF16() do { \
    __builtin_amdgcn_s_setprio(1); \
    _Pragma("unroll") \
    for (int m = 0; m < 4; ++m) \
        _Pragma("unroll") \
        for (int n = 0; n < 4; ++n) \
            acc[m][n] = __builtin_amdgcn_mfma_f32_16x16x32_bf16(af[m], bf[n], acc[m][n], 0, 0, 0); \
    __builtin_amdgcn_s_setprio(0); \
} while (0)

#define VMCNT0() asm volatile("s_waitcnt vmcnt(0)" ::: "memory")
#define LGKM0()  asm volatile("s_waitcnt lgkmcnt(0)" ::: "memory")

    // ---------------- prologue: stage tile 0 ----------------
    stage_half(Asrc,  K, 0, As, t);
    stage_half(Bsrc0, K, 0, Bs, t);
    stage_half(Bsrc1, K, 0, Bs + 16384, t);
    VMCNT0();
    BAR();

    const int NT = K >> 6;   // 16 K-tiles
    for (int kt = 0; kt < NT; ++kt) {
        const bool more = (kt + 1) < NT;

        RDA(x0); RDB(x0);
        MF16();                       // ks0 (LDS latency hidden by 4 waves/SIMD)
        RDA(x1); RDB(x1);             // ks1 into same regs (ks0 frags dead)
        LGKM0();                      // all this wave's LDS reads complete
        BAR();                        // all waves done reading the buffer
        if (more) {
            stage_half(Asrc,  K, kt + 1, As, t);
            stage_half(Bsrc0, K, kt + 1, Bs, t);
            stage_half(Bsrc1, K, kt + 1, Bs + 16384, t);
        }
        MF16();                       // ks1 on regs; stage DMA flies underneath
        if (more) { VMCNT0(); }       // stage complete (drain overlaps co-block)
        BAR();
    }

    // ---------------- epilogue: alpha * acc + bias ----------------
    const float alpha = *alphap;
    float bv[4];
    #pragma unroll
    for (int nf = 0; nf < 4; ++nf) bv[nf] = bias[bn0 + (wn << 6) + (nf << 4) + lr];

    #pragma unroll
    for (int mf = 0; mf < 4; ++mf) {
        const int grow = bm0 + (wm << 6) + (mf << 4) + (hi << 2);
        #pragma unroll
        for (int nf = 0; nf < 4; ++nf) {
            const int gcol = bn0 + (wn << 6) + (nf << 4) + lr;
            #pragma unroll
            for (int r = 0; r < 4; ++r)
                C[(size_t)(grow + r) * N + gcol] = alpha * acc[mf][nf][r] + bv[nf];
        }
    }
#undef RDA
#undef RDB
#undef MF16
#undef VMCNT0
#undef LGKM0
}

// ---------- fallback GEMM (round-1 proven): fp32 A staged in-kernel ----------
__global__ __launch_bounds__(256) void k_gemm_fb(const float* __restrict__ A,
                                                 const bf16* __restrict__ Bw,
                                                 const float* __restrict__ alphap,
                                                 const float* __restrict__ bias,
                                                 float* __restrict__ C,
                                                 int M, int N, int K) {
    __shared__ bf16 As[128 * 32];
    __shared__ bf16 Bs[128 * 32];
    const int t = threadIdx.x, lane = t & 63, wave = t >> 6;
    const int nbm = M >> 7;
    const int bm0 = (blockIdx.x % nbm) << 7;
    const int bn0 = (blockIdx.x / nbm) << 7;
    const int wr = (wave >> 1) << 6, wc = (wave & 1) << 6;
    f32x4 acc[4][4] = {};
    const int lr = lane & 15, lk = (lane >> 4) << 3;
    for (int k0 = 0; k0 < K; k0 += 32) {
        #pragma unroll
        for (int j = 0; j < 2; ++j) {
            const int c = t + j * 256;
            async_load16(Bw + (size_t)(bn0 + (c >> 2)) * K + k0 + ((c & 3) << 3),
                         (char*)Bs + j * 4096 + wave * 1024);
        }
        #pragma unroll
        for (int i = 0; i < 4; ++i) {
            const int idx = t + i * 256;
            const int row = idx >> 3, c4 = (idx & 7) << 2;
            const float4 v = *(const float4*)(A + (size_t)(bm0 + row) * K + k0 + c4);
            bf16x4 h;
            h[0] = (bf16)v.x; h[1] = (bf16)v.y; h[2] = (bf16)v.z; h[3] = (bf16)v.w;
            *(bf16x4*)(As + row * 32 + c4) = h;
        }
        __syncthreads();
        bf16x8 af[4], bfr[4];
        #pragma unroll
        for (int m = 0; m < 4; ++m) af[m] = *(const bf16x8*)(As + (wr + m * 16 + lr) * 32 + lk);
        #pragma unroll
        for (int n = 0; n < 4; ++n) bfr[n] = *(const bf16x8*)(Bs + (wc + n * 16 + lr) * 32 + lk);
        #pragma unroll
        for (int m = 0; m < 4; ++m)
            #pragma unroll
            for (int n = 0; n < 4; ++n)
                acc[m][n] = __builtin_amdgcn_mfma_f32_16x16x32_bf16(af[m], bfr[n], acc[m][n], 0, 0, 0);
        __syncthreads();
    }
    const float alpha = *alphap;
    #pragma unroll
    for (int m = 0; m < 4; ++m)
        #pragma unroll
        for (int n = 0; n < 4; ++n) {
            const int gcol = bn0 + wc + n * 16 + lr;
            const float bv = bias[gcol];
            #pragma unroll
            for (int r = 0; r < 4; ++r) {
                const int grow = bm0 + wr + m * 16 + ((lane >> 4) << 2) + r;
                C[(size_t)grow * N + gcol] = alpha * acc[m][n][r] + bv;
            }
        }
}

extern "C" void kernel_launch(void* const* d_in, const int* in_sizes, int n_in,
                              void* d_out, int out_size, void* d_ws, size_t ws_size,
                              hipStream_t stream) {
    const float* x     = (const float*)d_in[0];
    const float* wgt   = (const float*)d_in[1];
    const float* alpha = (const float*)d_in[2];
    const float* bias  = (const float*)d_in[3];
    float* out = (float*)d_out;

    const int wn   = in_sizes[1];        // 1048576
    const int dout = in_sizes[3];        // 1024
    const int din  = wn / dout;          // 1024
    const int m    = in_sizes[0] / din;  // 32768

    char* ws = (char*)d_ws;
    double* part = (double*)(ws + 64);          // 256 doubles
    bf16*   wt   = (bf16*)(ws + 8192);          // 2 MiB ternary weights
    bf16*   abf  = (bf16*)(ws + (4u << 20));    // 64 MiB bf16 A

    const size_t need = (4u << 20) + (size_t)in_sizes[0] * 2;
    const bool use2 = (ws_size >= need) && (m % 128) == 0 && (dout % 256) == 0 &&
                      (din % 64) == 0 && ((m / 128) * (dout / 256)) % 8 == 0;

    if (use2) {
        // blocks [0,256): |W| partials;  [256,2304): A fp32->bf16 convert
        k_absconv<<<2304, 256, 0, stream>>>(wgt, wn, part, x, abf, in_sizes[0] / 8);
        k_quantW<<<512, 256, 0, stream>>>(wgt, part, wt, wn / 4, wn);
        dim3 grid((m / 128) * (dout / 256));
        k_gemm2<<<grid, 512, 0, stream>>>(abf, wt, alpha, bias, out, m, dout, din);
    } else {
        k_absconv<<<256, 256, 0, stream>>>(wgt, wn, part, x, nullptr, 0);
        k_quantW<<<512, 256, 0, stream>>>(wgt, part, wt, wn / 4, wn);
        dim3 grid((m / 128) * (dout / 128));
        k_gemm_fb<<<grid, 256, 0, stream>>>(x, wt, alpha, bias, out, m, dout, din);
    }
}